// Round 2
// baseline (399.207 us; speedup 1.0000x reference)
//
#include <hip/hip_runtime.h>
#include <math.h>

// Problem constants: T=4, V=2, L=3, N=4000, D=256, TEMP=0.5
#define DD 256
#define NV 2
#define NL 3
#define NNODE 4000
// Row table: B-rows (anchors at all 6 (x,y)) then C-rows (cross negatives).
//   B: t0 [0,3600) S=100 | t1 [3600,7200) | t2 [7200,7920) S=20 | t3 [7920,8640)
//   C: t0 [8640,9540) K=50 | t1 [9540,10440) | t2 [10440,10620) K=10 | t3 [10620,10800)
#define NROWS_B 8640
#define NROWS 10800
#define ACC_OFF (10800L * 256)  // float offset in ws of accumulators
#define NANCH 1440              // total anchors = 2*600 + 2*120

__device__ __forceinline__ int tb_B(int t) { return (t < 2) ? t * 3600 : 7200 + (t - 2) * 720; }
__device__ __forceinline__ int tb_C(int t) { return (t < 2) ? t * 900 : 1800 + (t - 2) * 180; }
__device__ __forceinline__ int anch_base(int t, int vl) {
  return ((t < 2) ? t * 600 : 1200 + (t - 2) * 120) + vl * ((t < 2) ? 100 : 20);
}
// ws row id of anchor z(t,v,l,s) = B row with xy == (v,l)
__device__ __forceinline__ int zrow_id(int t, int v, int l, int s, int S) {
  int vl = v * NL + l;
  return tb_B(t) + ((vl * NV + v) * NL + l) * S + s;
}

// Map flat row id u -> source offset (floats) in E. Wave-uniform.
__device__ __forceinline__ long row_src(int u, const int* __restrict__ ip,
                                        const int* __restrict__ ir,
                                        const int* __restrict__ npg,
                                        const int* __restrict__ nrg) {
  int t, x, y, node;
  if (u < NROWS_B) {
    int S, u2;
    if (u < 7200) { t = u / 3600; u2 = u - t * 3600; S = 100; }
    else { int w = u - 7200; t = 2 + w / 720; u2 = w % 720; S = 20; }
    int s = u2 % S; int t1 = u2 / S;
    int l = t1 % NL; int t2 = t1 / NL;
    int v = t2 % NV; int xy = t2 / NV;
    x = xy / NL; y = xy % NL;
    if (t < 2) node = ip[((t * NV + v) * NL + l) * 100 + s];
    else       node = ir[(((t - 2) * NV + v) * NL + l) * 20 + s];
  } else {
    int w = u - NROWS_B;
    int K, u2;
    if (w < 1800) { t = w / 900; u2 = w % 900; K = 50; }
    else { int w2 = w - 1800; t = 2 + w2 / 180; u2 = w2 % 180; K = 10; }
    int k = u2 % K; int t1 = u2 / K;
    int l = t1 % NL; int t2 = t1 / NL;
    int v = t2 % NV; int o = t2 / NV;
    if (t < 2) node = npg[(((t * NV + v) * NL + l) * 3 + o) * 50 + k];
    else       node = nrg[((((t - 2) * NV + v) * NL + l) * 3 + o) * 10 + k];
    int ot = (o < t) ? o : o + 1;  // others[o] for type t
    t = ot; x = v; y = l;
  }
  return ((((long)t * NV + x) * NL + y) * NNODE + node) * DD;
}

// K1 v2: 32 rows/block; thread = (rowgroup rg=tid>>5, 8 cols c=(tid&31)+32j).
// acc[4][8]; per 4k-step: 4 LDS b128 (X rows, reused over 8 cols) + 8 global
// b128 (W) -> 128 FMA. VALU-bound (LDS feeds 32 FMA per ds_read_b128).
__global__ __launch_bounds__(256) void k_proj(const float* __restrict__ E,
                                              const float* __restrict__ W1,
                                              const float* __restrict__ b1,
                                              const float* __restrict__ W2,
                                              const float* __restrict__ b2,
                                              const int* __restrict__ ip,
                                              const int* __restrict__ ir,
                                              const int* __restrict__ npg,
                                              const int* __restrict__ nrg,
                                              float* __restrict__ ws) {
  __shared__ float X[32][DD];
  __shared__ float H[32][DD];
  const int tid = threadIdx.x;
  const int u0 = blockIdx.x * 32;
  const int lane32 = tid & 31;
  const int rg = tid >> 5;          // 0..7, rows rg*4..rg*4+3
  const int wv = tid >> 6;          // wave id 0..3
  const int l64 = tid & 63;

  // gather: each wave stages one row per iteration (1 KB coalesced float4)
  for (int r4 = 0; r4 < 8; ++r4) {
    int r = r4 * 4 + wv;
    int u = u0 + r;
    float4 val = make_float4(0.f, 0.f, 0.f, 0.f);
    if (u < NROWS) {
      long src = row_src(u, ip, ir, npg, nrg);   // wave-uniform
      val = *(const float4*)(E + src + l64 * 4);
    }
    *(float4*)(&X[r][l64 * 4]) = val;
  }
  __syncthreads();

  float acc[4][8];
  int cj[8];
#pragma unroll
  for (int j = 0; j < 8; ++j) cj[j] = lane32 + 32 * j;

  // stage 1
#pragma unroll
  for (int j = 0; j < 8; ++j) {
    float bv = b1[cj[j]];
#pragma unroll
    for (int r = 0; r < 4; ++r) acc[r][j] = bv;
  }
  for (int k4 = 0; k4 < 64; ++k4) {
    float4 xv[4];
#pragma unroll
    for (int r = 0; r < 4; ++r) xv[r] = *(const float4*)(&X[rg * 4 + r][k4 * 4]);
#pragma unroll
    for (int j = 0; j < 8; ++j) {
      float4 w = *(const float4*)(W1 + (long)cj[j] * DD + k4 * 4);
#pragma unroll
      for (int r = 0; r < 4; ++r) {
        acc[r][j] = fmaf(w.x, xv[r].x, acc[r][j]);
        acc[r][j] = fmaf(w.y, xv[r].y, acc[r][j]);
        acc[r][j] = fmaf(w.z, xv[r].z, acc[r][j]);
        acc[r][j] = fmaf(w.w, xv[r].w, acc[r][j]);
      }
    }
  }
  __syncthreads();   // X no longer needed before H written? X/H separate; sync for H readers
#pragma unroll
  for (int r = 0; r < 4; ++r)
#pragma unroll
    for (int j = 0; j < 8; ++j) H[rg * 4 + r][cj[j]] = fmaxf(acc[r][j], 0.0f);
  __syncthreads();

  // stage 2
#pragma unroll
  for (int j = 0; j < 8; ++j) {
    float bv = b2[cj[j]];
#pragma unroll
    for (int r = 0; r < 4; ++r) acc[r][j] = bv;
  }
  for (int k4 = 0; k4 < 64; ++k4) {
    float4 xv[4];
#pragma unroll
    for (int r = 0; r < 4; ++r) xv[r] = *(const float4*)(&H[rg * 4 + r][k4 * 4]);
#pragma unroll
    for (int j = 0; j < 8; ++j) {
      float4 w = *(const float4*)(W2 + (long)cj[j] * DD + k4 * 4);
#pragma unroll
      for (int r = 0; r < 4; ++r) {
        acc[r][j] = fmaf(w.x, xv[r].x, acc[r][j]);
        acc[r][j] = fmaf(w.y, xv[r].y, acc[r][j]);
        acc[r][j] = fmaf(w.z, xv[r].z, acc[r][j]);
        acc[r][j] = fmaf(w.w, xv[r].w, acc[r][j]);
      }
    }
  }

  // norm: rows rg*4+r owned by the 32 lanes of this half-wave (lanes rg%2*32..)
  float ss[4];
#pragma unroll
  for (int r = 0; r < 4; ++r) {
    float s = 0.f;
#pragma unroll
    for (int j = 0; j < 8; ++j) s = fmaf(acc[r][j], acc[r][j], s);
    ss[r] = s;
  }
  for (int off = 16; off > 0; off >>= 1) {
#pragma unroll
    for (int r = 0; r < 4; ++r) ss[r] += __shfl_xor(ss[r], off, 32);
  }
#pragma unroll
  for (int r = 0; r < 4; ++r) {
    int u = u0 + rg * 4 + r;
    if (u < NROWS) {
      float sc = 1.0f / fmaxf(sqrtf(ss[r]), 1e-12f);
#pragma unroll
      for (int j = 0; j < 8; ++j) ws[(long)u * DD + cj[j]] = acc[r][j] * sc;
    }
  }
}

// K0: zero pos/neg accumulators
__global__ __launch_bounds__(256) void k_zero(float* __restrict__ ws) {
  int i = blockIdx.x * 256 + threadIdx.x;
  if (i < 2 * NANCH) ws[ACC_OFF + i] = 0.0f;
}

// K2 v2: grid 144 = (t, vl, xy). 4 lanes per dot; global atomicAdd into pos.
__global__ __launch_bounds__(256) void k_pos(float* __restrict__ ws) {
  const int b = blockIdx.x;
  const int t = b / 36, r = b % 36, vl = r / 6, xy = r % 6;
  if (xy == vl) return;
  const int v = vl / NL, l = vl % NL;
  const int S = (t < 2) ? 100 : 20;
  const int tid = threadIdx.x;
  const int sub = tid & 3;
  const int ab = anch_base(t, vl);
  for (int s0 = 0; s0 < S; s0 += 64) {
    int s = s0 + (tid >> 2);
    if (s >= S) break;
    const float4* za = (const float4*)(ws + (long)zrow_id(t, v, l, s, S) * DD);
    const float4* pa = (const float4*)(ws + (long)(tb_B(t) + ((xy * NV + v) * NL + l) * S + s) * DD);
    float d = 0.0f;
#pragma unroll
    for (int i = 0; i < 16; ++i) {
      float4 a = za[sub + 4 * i];
      float4 bb = pa[sub + 4 * i];
      d = fmaf(a.x, bb.x, d); d = fmaf(a.y, bb.y, d);
      d = fmaf(a.z, bb.z, d); d = fmaf(a.w, bb.w, d);
    }
    d += __shfl_xor(d, 1, 4);
    d += __shfl_xor(d, 2, 4);
    if (sub == 0) atomicAdd(&ws[ACC_OFF + ab + s], expf(2.0f * d));
  }
}

// K3 v2: grid 228 = (t, vl, anchor-half, partner-chunk-32). Z and P tiles staged
// once for full K; Z cached in regs per 8-k chunk; acc[4][2] per thread.
#define ZPAD 260
__global__ __launch_bounds__(256) void k_neg(float* __restrict__ ws) {
  __shared__ float Zt[64][ZPAD];
  __shared__ float Pt[32][ZPAD];
  const int b = blockIdx.x;
  int t, vl, c, A0, A;
  if (b < 192) { t = b / 96; int r = b % 96; vl = r / 16; int w = r % 16;
                 A0 = (w / 8) * 50; A = 50; c = w % 8; }
  else { int q = b - 192; t = 2 + q / 18; int r2 = q % 18; vl = r2 / 3;
         c = r2 % 3; A0 = 0; A = 20; }
  const int v = vl / NL, l = vl % NL;
  const int S = (t < 2) ? 100 : 20, K = (t < 2) ? 50 : 10;
  const int Ptot = S + 3 * K;          // 250 or 80... (S+3K: 250 / 50)
  const int q0 = c * 32;
  const int pn = min(32, Ptot - q0);
  const int tid = threadIdx.x;
  const int tx = tid & 15, ty = tid >> 4;   // partner lane / anchor lane

  // stage Z rows (A x 256), coalesced
  for (int e = tid; e < A * 64; e += 256) {
    int a = e >> 6, kk = (e & 63) * 4;
    long zr = (long)zrow_id(t, v, l, A0 + a, S) * DD;
    *(float4*)(&Zt[a][kk]) = *(const float4*)(ws + zr + kk);
  }
  // stage P rows (pn x 256), coalesced
  for (int e = tid; e < pn * 64; e += 256) {
    int p = e >> 6, kk = (e & 63) * 4;
    int qg = q0 + p;
    long row;
    if (qg < S) row = zrow_id(t, v, l, qg, S);
    else { int q2 = qg - S; int o = q2 / K, k2 = q2 % K;
           row = NROWS_B + tb_C(t) + ((o * NV + v) * NL + l) * K + k2; }
    *(float4*)(&Pt[p][kk]) = *(const float4*)(ws + row * DD + kk);
  }
  __syncthreads();

  float acc[4][2];
#pragma unroll
  for (int i = 0; i < 4; ++i) { acc[i][0] = 0.f; acc[i][1] = 0.f; }

  for (int k0 = 0; k0 < DD; k0 += 8) {
    float4 zr0[4], zr1[4];
#pragma unroll
    for (int i = 0; i < 4; ++i) {
      zr0[i] = *(const float4*)(&Zt[ty + 16 * i][k0]);
      zr1[i] = *(const float4*)(&Zt[ty + 16 * i][k0 + 4]);
    }
#pragma unroll
    for (int j = 0; j < 2; ++j) {
      float4 p0 = *(const float4*)(&Pt[tx + 16 * j][k0]);
      float4 p1 = *(const float4*)(&Pt[tx + 16 * j][k0 + 4]);
#pragma unroll
      for (int i = 0; i < 4; ++i) {
        float s = acc[i][j];
        s = fmaf(zr0[i].x, p0.x, s); s = fmaf(zr0[i].y, p0.y, s);
        s = fmaf(zr0[i].z, p0.z, s); s = fmaf(zr0[i].w, p0.w, s);
        s = fmaf(zr1[i].x, p1.x, s); s = fmaf(zr1[i].y, p1.y, s);
        s = fmaf(zr1[i].z, p1.z, s); s = fmaf(zr1[i].w, p1.w, s);
        acc[i][j] = s;
      }
    }
  }

  // epilogue: mask + exp + reduce over tx, atomicAdd per anchor
#pragma unroll
  for (int i = 0; i < 4; ++i) {
    int a = ty + 16 * i;          // local anchor
    float sum = 0.0f;
    if (a < A) {
      int sg = A0 + a;            // global anchor index within (t,vl)
#pragma unroll
      for (int j = 0; j < 2; ++j) {
        int qg = q0 + tx + 16 * j;
        if (qg < Ptot && !(qg < S && qg == sg)) sum += expf(2.0f * acc[i][j]);
      }
    }
    for (int o = 8; o > 0; o >>= 1) sum += __shfl_xor(sum, o, 16);
    if (a < A && tx == 0)
      atomicAdd(&ws[ACC_OFF + NANCH + anch_base(t, vl) + A0 + a], sum);
  }
}

// K4: loss = mean over anchors of -log(pos/(pos+neg))
__global__ __launch_bounds__(256) void k_fin(const float* __restrict__ ws,
                                             float* __restrict__ out) {
  __shared__ float red[256];
  const int tid = threadIdx.x;
  float sum = 0.0f;
  for (int i = tid; i < NANCH; i += 256) {
    float p = ws[ACC_OFF + i];
    float n = ws[ACC_OFF + NANCH + i];
    sum += -logf(p / (p + n));
  }
  red[tid] = sum;
  __syncthreads();
  for (int s = 128; s > 0; s >>= 1) {
    if (tid < s) red[tid] += red[tid + s];
    __syncthreads();
  }
  if (tid == 0) out[0] = red[0] / (float)NANCH;
}

extern "C" void kernel_launch(void* const* d_in, const int* in_sizes, int n_in,
                              void* d_out, int out_size, void* d_ws, size_t ws_size,
                              hipStream_t stream) {
  const float* E  = (const float*)d_in[0];
  const float* W1 = (const float*)d_in[1];
  const float* b1 = (const float*)d_in[2];
  const float* W2 = (const float*)d_in[3];
  const float* b2 = (const float*)d_in[4];
  const int* ip  = (const int*)d_in[5];
  const int* ir  = (const int*)d_in[6];
  const int* npg = (const int*)d_in[7];
  const int* nrg = (const int*)d_in[8];
  float* ws = (float*)d_ws;   // ~11.1 MB: 10800 rows*256 fp32 + 2*1440 accumulators
  float* out = (float*)d_out;

  hipLaunchKernelGGL(k_proj, dim3((NROWS + 31) / 32), dim3(256), 0, stream,
                     E, W1, b1, W2, b2, ip, ir, npg, nrg, ws);
  hipLaunchKernelGGL(k_zero, dim3(12), dim3(256), 0, stream, ws);
  hipLaunchKernelGGL(k_pos, dim3(144), dim3(256), 0, stream, ws);
  hipLaunchKernelGGL(k_neg, dim3(228), dim3(256), 0, stream, ws);
  hipLaunchKernelGGL(k_fin, dim3(1), dim3(256), 0, stream, ws, out);
}

// Round 3
// 204.253 us; speedup vs baseline: 1.9545x; 1.9545x over previous
//
#include <hip/hip_runtime.h>
#include <math.h>

// Problem constants: T=4, V=2, L=3, N=4000, D=256, TEMP=0.5
#define DD 256
#define NV 2
#define NL 3
#define NNODE 4000
// Row table: B-rows (anchors at all 6 (x,y)) then C-rows (cross negatives).
#define NROWS_B 8640
#define NROWS 10800
#define ACC_OFF (10800L * 256)          // float offset of accumulators (pos|neg, 2*1440)
#define NANCH 1440
#define WP_OFF (ACC_OFF + 2 * NANCH)    // float offset of frag-ordered bf16 W' (131072 ushort)
#define XPAD 260                        // bf16 units per LDS row (256 + 4 pad)

typedef __attribute__((ext_vector_type(8))) short short8;
typedef __attribute__((ext_vector_type(4))) short short4v;
typedef __attribute__((ext_vector_type(4))) float f32x4;

__device__ __forceinline__ unsigned short f2bf(float f) {
  unsigned u = __float_as_uint(f);
  u += 0x7fff + ((u >> 16) & 1);   // RNE
  return (unsigned short)(u >> 16);
}

__device__ __forceinline__ int tb_B(int t) { return (t < 2) ? t * 3600 : 7200 + (t - 2) * 720; }
__device__ __forceinline__ int tb_C(int t) { return (t < 2) ? t * 900 : 1800 + (t - 2) * 180; }
__device__ __forceinline__ int anch_base(int t, int vl) {
  return ((t < 2) ? t * 600 : 1200 + (t - 2) * 120) + vl * ((t < 2) ? 100 : 20);
}
__device__ __forceinline__ int zrow_id(int t, int v, int l, int s, int S) {
  int vl = v * NL + l;
  return tb_B(t) + ((vl * NV + v) * NL + l) * S + s;
}

// Map flat row id u -> source offset (floats) in E. Wave-uniform.
__device__ __forceinline__ long row_src(int u, const int* __restrict__ ip,
                                        const int* __restrict__ ir,
                                        const int* __restrict__ npg,
                                        const int* __restrict__ nrg) {
  int t, x, y, node;
  if (u < NROWS_B) {
    int S, u2;
    if (u < 7200) { t = u / 3600; u2 = u - t * 3600; S = 100; }
    else { int w = u - 7200; t = 2 + w / 720; u2 = w % 720; S = 20; }
    int s = u2 % S; int t1 = u2 / S;
    int l = t1 % NL; int t2 = t1 / NL;
    int v = t2 % NV; int xy = t2 / NV;
    x = xy / NL; y = xy % NL;
    if (t < 2) node = ip[((t * NV + v) * NL + l) * 100 + s];
    else       node = ir[(((t - 2) * NV + v) * NL + l) * 20 + s];
  } else {
    int w = u - NROWS_B;
    int K, u2;
    if (w < 1800) { t = w / 900; u2 = w % 900; K = 50; }
    else { int w2 = w - 1800; t = 2 + w2 / 180; u2 = w2 % 180; K = 10; }
    int k = u2 % K; int t1 = u2 / K;
    int l = t1 % NL; int t2 = t1 / NL;
    int v = t2 % NV; int o = t2 / NV;
    if (t < 2) node = npg[(((t * NV + v) * NL + l) * 3 + o) * 50 + k];
    else       node = nrg[((((t - 2) * NV + v) * NL + l) * 3 + o) * 10 + k];
    int ot = (o < t) ? o : o + 1;
    t = ot; x = v; y = l;
  }
  return ((((long)t * NV + x) * NL + y) * NNODE + node) * DD;
}

// K-1: build frag-ordered bf16 W' and zero pos/neg accumulators.
// W'[st][cg][kstep][lane][j]: value W_st[cg*16 + (lane&15)][kstep*32 + (lane>>4)*8 + j]
__global__ __launch_bounds__(256) void k_prep(const float* __restrict__ W1,
                                              const float* __restrict__ W2,
                                              float* __restrict__ ws) {
  int tid = blockIdx.x * 256 + threadIdx.x;   // grid 64 -> 16384 threads
  if (tid < 2 * NANCH) ws[ACC_OFF + tid] = 0.0f;
  int st = tid >> 13, rem = tid & 8191;
  int cg = rem >> 9, kstep = (rem >> 6) & 7, lane = rem & 63;
  const float* W = st ? W2 : W1;
  int col = cg * 16 + (lane & 15);
  int k0 = kstep * 32 + (lane >> 4) * 8;
  unsigned short v[8] __attribute__((aligned(16)));
#pragma unroll
  for (int j = 0; j < 8; ++j) v[j] = f2bf(W[col * DD + k0 + j]);
  unsigned short* wp = (unsigned short*)(ws + WP_OFF);
  *(uint4*)(wp + (long)tid * 8) = *(const uint4*)v;
}

// K1 v3: MFMA projection. Block = 32 rows, 4 waves; wave (rhalf,chalf) computes
// rows rhalf*16+[0,16) x cols chalf*128+[0,128). A-frags from LDS bf16 (X then H),
// B-frags coalesced from global W'. Accumulate fp32, fuse relu + L2-normalize.
__global__ __launch_bounds__(256) void k_proj(const float* __restrict__ E,
                                              const float* __restrict__ b1,
                                              const float* __restrict__ b2,
                                              const int* __restrict__ ip,
                                              const int* __restrict__ ir,
                                              const int* __restrict__ npg,
                                              const int* __restrict__ nrg,
                                              float* __restrict__ ws) {
  __shared__ unsigned short Xs[32][XPAD];
  __shared__ unsigned short Hs[32][XPAD];
  __shared__ float ssbuf[2][32];
  const int tid = threadIdx.x;
  const int u0 = blockIdx.x * 32;
  const int wv = tid >> 6, l64 = tid & 63;
  const int quad = l64 >> 4, l15 = l64 & 15;
  const int rhalf = wv & 1, chalf = wv >> 1;
  const int rb = rhalf * 16, cb = chalf * 128;
  const unsigned short* wp = (const unsigned short*)(ws + WP_OFF);

  // gather + fp32->bf16 convert; 8 rows per wave, 1 KB coalesced each
  for (int i = 0; i < 8; ++i) {
    int r = wv * 8 + i;
    int u = u0 + r;
    float4 val = make_float4(0.f, 0.f, 0.f, 0.f);
    if (u < NROWS) {
      long src = row_src(u, ip, ir, npg, nrg);   // wave-uniform
      val = *(const float4*)(E + src + l64 * 4);
    }
    unsigned short h[4] __attribute__((aligned(8)));
    h[0] = f2bf(val.x); h[1] = f2bf(val.y); h[2] = f2bf(val.z); h[3] = f2bf(val.w);
    *(uint2*)(&Xs[r][l64 * 4]) = *(const uint2*)h;
  }

  f32x4 acc[8];
  // ---- stage 1: H = relu(X @ W1^T + b1) ----
#pragma unroll
  for (int cg = 0; cg < 8; ++cg) {
    float bv = b1[cb + cg * 16 + l15];
    acc[cg] = (f32x4){bv, bv, bv, bv};
  }
  __syncthreads();
#pragma unroll
  for (int ks = 0; ks < 8; ++ks) {
    const unsigned short* ap = &Xs[rb + l15][ks * 32 + quad * 8];
    short4v alo = *(const short4v*)(ap);
    short4v ahi = *(const short4v*)(ap + 4);
    short8 a = __builtin_shufflevector(alo, ahi, 0, 1, 2, 3, 4, 5, 6, 7);
#pragma unroll
    for (int cg = 0; cg < 8; ++cg) {
      short8 b = *(const short8*)(wp + ((long)(((chalf * 8 + cg) * 8 + ks) * 64 + l64)) * 8);
      acc[cg] = __builtin_amdgcn_mfma_f32_16x16x32_bf16(a, b, acc[cg], 0, 0, 0);
    }
  }
#pragma unroll
  for (int cg = 0; cg < 8; ++cg) {
    int col = cb + cg * 16 + l15;
#pragma unroll
    for (int reg = 0; reg < 4; ++reg) {
      int row = rb + quad * 4 + reg;                 // C/D: col=lane&15, row=quad*4+reg
      Hs[row][col] = f2bf(fmaxf(acc[cg][reg], 0.0f));
    }
  }
  // ---- stage 2: Z = H @ W2^T + b2 ----
#pragma unroll
  for (int cg = 0; cg < 8; ++cg) {
    float bv = b2[cb + cg * 16 + l15];
    acc[cg] = (f32x4){bv, bv, bv, bv};
  }
  __syncthreads();
#pragma unroll
  for (int ks = 0; ks < 8; ++ks) {
    const unsigned short* ap = &Hs[rb + l15][ks * 32 + quad * 8];
    short4v alo = *(const short4v*)(ap);
    short4v ahi = *(const short4v*)(ap + 4);
    short8 a = __builtin_shufflevector(alo, ahi, 0, 1, 2, 3, 4, 5, 6, 7);
#pragma unroll
    for (int cg = 0; cg < 8; ++cg) {
      short8 b = *(const short8*)(wp + ((long)((16 + chalf * 8 + cg) * 8 + ks) * 64 + l64) * 8);
      acc[cg] = __builtin_amdgcn_mfma_f32_16x16x32_bf16(a, b, acc[cg], 0, 0, 0);
    }
  }
  // ---- normalize (fp32) + store ----
  float ss[4];
#pragma unroll
  for (int reg = 0; reg < 4; ++reg) {
    float s = 0.f;
#pragma unroll
    for (int cg = 0; cg < 8; ++cg) s = fmaf(acc[cg][reg], acc[cg][reg], s);
    ss[reg] = s;
  }
#pragma unroll
  for (int m = 1; m < 16; m <<= 1) {
#pragma unroll
    for (int reg = 0; reg < 4; ++reg) ss[reg] += __shfl_xor(ss[reg], m, 64);
  }
  if (l15 == 0) {
#pragma unroll
    for (int reg = 0; reg < 4; ++reg) ssbuf[chalf][rb + quad * 4 + reg] = ss[reg];
  }
  __syncthreads();
#pragma unroll
  for (int reg = 0; reg < 4; ++reg) {
    int row = rb + quad * 4 + reg;
    int u = u0 + row;
    if (u < NROWS) {
      float tot = ssbuf[0][row] + ssbuf[1][row];
      float sc = 1.0f / fmaxf(sqrtf(tot), 1e-12f);
#pragma unroll
      for (int cg = 0; cg < 8; ++cg)
        ws[(long)u * DD + cb + cg * 16 + l15] = acc[cg][reg] * sc;
    }
  }
}

// K2: grid 144 = (t, vl, xy). 4 lanes per dot; global atomicAdd into pos.
__global__ __launch_bounds__(256) void k_pos(float* __restrict__ ws) {
  const int b = blockIdx.x;
  const int t = b / 36, r = b % 36, vl = r / 6, xy = r % 6;
  if (xy == vl) return;
  const int v = vl / NL, l = vl % NL;
  const int S = (t < 2) ? 100 : 20;
  const int tid = threadIdx.x;
  const int sub = tid & 3;
  const int ab = anch_base(t, vl);
  for (int s0 = 0; s0 < S; s0 += 64) {
    int s = s0 + (tid >> 2);
    if (s >= S) break;
    const float4* za = (const float4*)(ws + (long)zrow_id(t, v, l, s, S) * DD);
    const float4* pa = (const float4*)(ws + (long)(tb_B(t) + ((xy * NV + v) * NL + l) * S + s) * DD);
    float d = 0.0f;
#pragma unroll
    for (int i = 0; i < 16; ++i) {
      float4 a = za[sub + 4 * i];
      float4 bb = pa[sub + 4 * i];
      d = fmaf(a.x, bb.x, d); d = fmaf(a.y, bb.y, d);
      d = fmaf(a.z, bb.z, d); d = fmaf(a.w, bb.w, d);
    }
    d += __shfl_xor(d, 1, 4);
    d += __shfl_xor(d, 2, 4);
    if (sub == 0) atomicAdd(&ws[ACC_OFF + ab + s], expf(2.0f * d));
  }
}

// K3: grid 228 = (t, vl, anchor-half, partner-chunk-32).
#define ZPAD2 260
__global__ __launch_bounds__(256) void k_neg(float* __restrict__ ws) {
  __shared__ float Zt[64][ZPAD2];
  __shared__ float Pt[32][ZPAD2];
  const int b = blockIdx.x;
  int t, vl, c, A0, A;
  if (b < 192) { t = b / 96; int r = b % 96; vl = r / 16; int w = r % 16;
                 A0 = (w / 8) * 50; A = 50; c = w % 8; }
  else { int q = b - 192; t = 2 + q / 18; int r2 = q % 18; vl = r2 / 3;
         c = r2 % 3; A0 = 0; A = 20; }
  const int v = vl / NL, l = vl % NL;
  const int S = (t < 2) ? 100 : 20, K = (t < 2) ? 50 : 10;
  const int Ptot = S + 3 * K;
  const int q0 = c * 32;
  const int pn = min(32, Ptot - q0);
  const int tid = threadIdx.x;
  const int tx = tid & 15, ty = tid >> 4;

  for (int e = tid; e < A * 64; e += 256) {
    int a = e >> 6, kk = (e & 63) * 4;
    long zr = (long)zrow_id(t, v, l, A0 + a, S) * DD;
    *(float4*)(&Zt[a][kk]) = *(const float4*)(ws + zr + kk);
  }
  for (int e = tid; e < pn * 64; e += 256) {
    int p = e >> 6, kk = (e & 63) * 4;
    int qg = q0 + p;
    long row;
    if (qg < S) row = zrow_id(t, v, l, qg, S);
    else { int q2 = qg - S; int o = q2 / K, k2 = q2 % K;
           row = NROWS_B + tb_C(t) + ((o * NV + v) * NL + l) * K + k2; }
    *(float4*)(&Pt[p][kk]) = *(const float4*)(ws + row * DD + kk);
  }
  __syncthreads();

  float acc[4][2];
#pragma unroll
  for (int i = 0; i < 4; ++i) { acc[i][0] = 0.f; acc[i][1] = 0.f; }

  for (int k0 = 0; k0 < DD; k0 += 8) {
    float4 zr0[4], zr1[4];
#pragma unroll
    for (int i = 0; i < 4; ++i) {
      zr0[i] = *(const float4*)(&Zt[ty + 16 * i][k0]);
      zr1[i] = *(const float4*)(&Zt[ty + 16 * i][k0 + 4]);
    }
#pragma unroll
    for (int j = 0; j < 2; ++j) {
      float4 p0 = *(const float4*)(&Pt[tx + 16 * j][k0]);
      float4 p1 = *(const float4*)(&Pt[tx + 16 * j][k0 + 4]);
#pragma unroll
      for (int i = 0; i < 4; ++i) {
        float s = acc[i][j];
        s = fmaf(zr0[i].x, p0.x, s); s = fmaf(zr0[i].y, p0.y, s);
        s = fmaf(zr0[i].z, p0.z, s); s = fmaf(zr0[i].w, p0.w, s);
        s = fmaf(zr1[i].x, p1.x, s); s = fmaf(zr1[i].y, p1.y, s);
        s = fmaf(zr1[i].z, p1.z, s); s = fmaf(zr1[i].w, p1.w, s);
        acc[i][j] = s;
      }
    }
  }

#pragma unroll
  for (int i = 0; i < 4; ++i) {
    int a = ty + 16 * i;
    float sum = 0.0f;
    if (a < A) {
      int sg = A0 + a;
#pragma unroll
      for (int j = 0; j < 2; ++j) {
        int qg = q0 + tx + 16 * j;
        if (qg < Ptot && !(qg < S && qg == sg)) sum += expf(2.0f * acc[i][j]);
      }
    }
    for (int o = 8; o > 0; o >>= 1) sum += __shfl_xor(sum, o, 16);
    if (a < A && tx == 0)
      atomicAdd(&ws[ACC_OFF + NANCH + anch_base(t, vl) + A0 + a], sum);
  }
}

// K4: loss = mean over anchors of -log(pos/(pos+neg))
__global__ __launch_bounds__(256) void k_fin(const float* __restrict__ ws,
                                             float* __restrict__ out) {
  __shared__ float red[256];
  const int tid = threadIdx.x;
  float sum = 0.0f;
  for (int i = tid; i < NANCH; i += 256) {
    float p = ws[ACC_OFF + i];
    float n = ws[ACC_OFF + NANCH + i];
    sum += -logf(p / (p + n));
  }
  red[tid] = sum;
  __syncthreads();
  for (int s = 128; s > 0; s >>= 1) {
    if (tid < s) red[tid] += red[tid + s];
    __syncthreads();
  }
  if (tid == 0) out[0] = red[0] / (float)NANCH;
}

extern "C" void kernel_launch(void* const* d_in, const int* in_sizes, int n_in,
                              void* d_out, int out_size, void* d_ws, size_t ws_size,
                              hipStream_t stream) {
  const float* E  = (const float*)d_in[0];
  const float* W1 = (const float*)d_in[1];
  const float* b1 = (const float*)d_in[2];
  const float* W2 = (const float*)d_in[3];
  const float* b2 = (const float*)d_in[4];
  const int* ip  = (const int*)d_in[5];
  const int* ir  = (const int*)d_in[6];
  const int* npg = (const int*)d_in[7];
  const int* nrg = (const int*)d_in[8];
  float* ws = (float*)d_ws;   // ~11.6 MB: z (10800x256 f32) + acc (2880 f32) + W' (512 KB bf16)
  float* out = (float*)d_out;

  hipLaunchKernelGGL(k_prep, dim3(64), dim3(256), 0, stream, W1, W2, ws);
  hipLaunchKernelGGL(k_proj, dim3((NROWS + 31) / 32), dim3(256), 0, stream,
                     E, b1, b2, ip, ir, npg, nrg, ws);
  hipLaunchKernelGGL(k_pos, dim3(144), dim3(256), 0, stream, ws);
  hipLaunchKernelGGL(k_neg, dim3(228), dim3(256), 0, stream, ws);
  hipLaunchKernelGGL(k_fin, dim3(1), dim3(256), 0, stream, ws, out);
}